// Round 9
// baseline (561.625 us; speedup 1.0000x reference)
//
#include <hip/hip_runtime.h>
#include <stdint.h>

// CoAttention, MI355X. B=4, C=2048, H=W=48 (HW=2304), HC=256.
// r9: PV restructured — B (attn) loaded DIRECTLY global->VGPR (1-tile prefetch,
// compiler-guarded), only A (V) staged via glds into ring-3 LDS (96 KB).
// LDS traffic/tile: 256KB -> 160KB (~625cyc ~= 621cyc MFMA). 1 barrier/tile.

#define NB 4
#define NC 2048
#define NHW 2304
#define NHC 256
#define NT 36  // K tiles of 64 over NHW

typedef _Float16 f16;
typedef __attribute__((ext_vector_type(4))) _Float16 f16x4;
typedef __attribute__((ext_vector_type(8))) _Float16 f16x8;
typedef __attribute__((ext_vector_type(4))) float f32x4;

static __device__ __forceinline__ void glds16(const void* g, void* lds) {
  __builtin_amdgcn_global_load_lds(
      (const __attribute__((address_space(1))) uint32_t*)g,
      (__attribute__((address_space(3))) uint32_t*)lds, 16, 0, 0);
}

// ---- prep: copy originals to out, X->f16 (Xh, [c][hw]) and X^T->f16 (Xt, [hw][c]) ----
__global__ __launch_bounds__(256) void k_prep(
    const float* __restrict__ xl, const float* __restrict__ xr,
    float* __restrict__ out, f16* __restrict__ Xh, f16* __restrict__ Xt) {
  const int z = blockIdx.z, side = z >> 2, b = z & 3;
  const float* X = (side ? xr : xl) + (size_t)b * NC * NHW;
  const int hw0 = blockIdx.x * 64, c0 = blockIdx.y * 64;
  const int t = threadIdx.x;
  const int colb = (t & 15) * 4;
  const int r0 = t >> 4;
  __shared__ f16 Lt[64 * 64];
  float* outb = out + (size_t)side * ((size_t)NB * 2 * NC * NHW) + (size_t)b * (2 * NC * NHW);
  f16* Xhb = Xh + (size_t)side * ((size_t)NB * NC * NHW) + (size_t)b * NC * NHW;
  f16* Xtb = Xt + (size_t)side * ((size_t)NB * NHW * NC) + (size_t)b * NHW * NC;
#pragma unroll
  for (int p = 0; p < 4; ++p) {
    int r = r0 + p * 16;
    size_t go = (size_t)(c0 + r) * NHW + hw0 + colb;
    float4 v = *(const float4*)&X[go];
    *(float4*)&outb[go] = v;
    f16x4 h; h[0] = (f16)v.x; h[1] = (f16)v.y; h[2] = (f16)v.z; h[3] = (f16)v.w;
    *(f16x4*)&Xhb[go] = h;
#pragma unroll
    for (int j = 0; j < 4; ++j) {
      int row = colb + j;
      int byte = row * 128 + ((r * 2) ^ ((((row >> 2) & 7)) << 4));
      *(f16*)((char*)Lt + byte) = h[j];
    }
  }
  __syncthreads();
#pragma unroll
  for (int p = 0; p < 2; ++p) {
    int idx = p * 256 + t;
    int row = idx >> 3, ch = idx & 7;
    int byte = row * 128 + (((ch ^ ((row >> 2) & 7))) << 4);
    f16x8 vv = *(const f16x8*)((char*)Lt + byte);
    *(f16x8*)&Xtb[(size_t)(hw0 + row) * NC + c0 + ch * 8] = vv;
  }
}

// ---- W stack to f16: Ws[512][2048] ----
__global__ __launch_bounds__(256) void k_w16(
    const float* __restrict__ wq, const float* __restrict__ wk, f16* __restrict__ Ws) {
  const int N4 = NHC * NC / 4;
  int idx = blockIdx.x * 256 + threadIdx.x;
  const float* src = (idx < N4) ? wq : wk;
  int e4 = (idx < N4) ? idx : idx - N4;
  float4 v = ((const float4*)src)[e4];
  f16x4 h; h[0] = (f16)v.x; h[1] = (f16)v.y; h[2] = (f16)v.z; h[3] = (f16)v.w;
  ((f16x4*)Ws)[idx] = h;
}

// ---- proj (both sides, z=side): Yt[i][512] = Ws x Xt + bias (128x128, BK=32) ----
__global__ __launch_bounds__(256) void k_proj(
    const f16* __restrict__ Ws, const f16* __restrict__ Xt0,
    const float* __restrict__ bq, const float* __restrict__ bk,
    f16* __restrict__ Yt0) {
  __shared__ f16 LA[2][128 * 32], LB[2][128 * 32];
  const int side = blockIdx.z;
  const f16* Xt = Xt0 + (size_t)side * ((size_t)NB * NHW * NC);
  f16* Yt = Yt0 + (size_t)side * ((size_t)NB * NHW * 512);
  const int n0 = blockIdx.x * 128;
  const int m0 = blockIdx.y * 128;
  const int tid = threadIdx.x, wv = tid >> 6, ln = tid & 63;
  const int lr = ln & 15, lh = ln >> 4;
  const int wm = wv >> 1, wn = wv & 1;
  f32x4 acc[4][4];
#pragma unroll
  for (int mi = 0; mi < 4; ++mi)
#pragma unroll
    for (int ni = 0; ni < 4; ++ni)
#pragma unroll
      for (int q = 0; q < 4; ++q) acc[mi][ni][q] = 0.f;

  auto stage = [&](int bi, int ks) {
    int k0 = ks * 32;
#pragma unroll
    for (int rep = 0; rep < 2; ++rep) {
      int u = rep * 256 + wv * 64 + ln;
      int r = u >> 2, k8 = (u & 3) * 8;
      int ub8 = (rep * 256 + wv * 64) * 8;
      glds16(Ws + (size_t)(m0 + r) * NC + k0 + k8, &LA[bi][ub8]);
      glds16(Xt + (size_t)(n0 + r) * NC + k0 + k8, &LB[bi][ub8]);
    }
  };
  auto compute = [&](int bi) {
    f16x8 af[4], bf[4];
#pragma unroll
    for (int mi = 0; mi < 4; ++mi)
      af[mi] = *(const f16x8*)&LA[bi][(wm * 64 + mi * 16 + lr) * 32 + lh * 8];
#pragma unroll
    for (int ni = 0; ni < 4; ++ni)
      bf[ni] = *(const f16x8*)&LB[bi][(wn * 64 + ni * 16 + lr) * 32 + lh * 8];
#pragma unroll
    for (int mi = 0; mi < 4; ++mi)
#pragma unroll
      for (int ni = 0; ni < 4; ++ni)
        acc[mi][ni] = __builtin_amdgcn_mfma_f32_16x16x32_f16(af[mi], bf[ni], acc[mi][ni], 0, 0, 0);
  };

  stage(0, 0);
  __syncthreads();
  int cur = 0;
  for (int ks = 0; ks < 63; ++ks) {
    stage(cur ^ 1, ks + 1);
    compute(cur);
    __syncthreads();
    cur ^= 1;
  }
  compute(cur);

#pragma unroll
  for (int mi = 0; mi < 4; ++mi)
#pragma unroll
    for (int ni = 0; ni < 4; ++ni) {
      int ob = m0 + wm * 64 + mi * 16 + lh * 4;
      int i = n0 + wn * 64 + ni * 16 + lr;
      f16x4 hv;
#pragma unroll
      for (int q = 0; q < 4; ++q) {
        int o = ob + q;
        float bias = (o < NHC) ? bq[o] : bk[o - NHC];
        hv[q] = (f16)(acc[mi][ni][q] + bias);
      }
      *(f16x4*)&Yt[(size_t)i * 512 + ob] = hv;
    }
}

// ---- scores (both dirs, z=dir*4+b offset by dir0): S[b][i][j] = sum_hc Q.K ----
__global__ __launch_bounds__(256) void k_scores(
    const f16* __restrict__ Yt, float* __restrict__ S0, float* __restrict__ S1,
    int dir0) {
  __shared__ f16 LA[2][128 * 32], LB[2][128 * 32];
  const size_t YTS = (size_t)NB * NHW * 512;
  const int z = blockIdx.z;
  const int dir = dir0 + (z >> 2);
  const int b = z & 3;
  const int i0 = blockIdx.x * 128, j0 = blockIdx.y * 128;
  const int tid = threadIdx.x, wv = tid >> 6, ln = tid & 63;
  const int lr = ln & 15, lh = ln >> 4;
  const int wm = wv >> 1, wn = wv & 1;
  const f16* Qb = Yt + (size_t)dir * YTS + (size_t)b * NHW * 512;
  const f16* Kb = Yt + (size_t)(1 - dir) * YTS + NHC + (size_t)b * NHW * 512;
  f32x4 acc[4][4];
#pragma unroll
  for (int mi = 0; mi < 4; ++mi)
#pragma unroll
    for (int ni = 0; ni < 4; ++ni)
#pragma unroll
      for (int q = 0; q < 4; ++q) acc[mi][ni][q] = 0.f;

  auto stage = [&](int bi, int ks) {
    int k0 = ks * 32;
#pragma unroll
    for (int rep = 0; rep < 2; ++rep) {
      int u = rep * 256 + wv * 64 + ln;
      int r = u >> 2, k8 = (u & 3) * 8;
      int ub8 = (rep * 256 + wv * 64) * 8;
      glds16(Qb + (size_t)(i0 + r) * 512 + k0 + k8, &LA[bi][ub8]);
      glds16(Kb + (size_t)(j0 + r) * 512 + k0 + k8, &LB[bi][ub8]);
    }
  };
  auto compute = [&](int bi) {
    f16x8 af[4], bf[4];
#pragma unroll
    for (int mi = 0; mi < 4; ++mi)
      af[mi] = *(const f16x8*)&LA[bi][(wm * 64 + mi * 16 + lr) * 32 + lh * 8];
#pragma unroll
    for (int ni = 0; ni < 4; ++ni)
      bf[ni] = *(const f16x8*)&LB[bi][(wn * 64 + ni * 16 + lr) * 32 + lh * 8];
#pragma unroll
    for (int mi = 0; mi < 4; ++mi)
#pragma unroll
      for (int ni = 0; ni < 4; ++ni)
        acc[mi][ni] = __builtin_amdgcn_mfma_f32_16x16x32_f16(af[mi], bf[ni], acc[mi][ni], 0, 0, 0);
  };

  stage(0, 0);
  __syncthreads();
  int cur = 0;
  for (int ks = 0; ks < 7; ++ks) {
    stage(cur ^ 1, ks + 1);
    compute(cur);
    __syncthreads();
    cur ^= 1;
  }
  compute(cur);

  float* Sb = (dir ? S1 : S0) + (size_t)b * NHW * NHW;
#pragma unroll
  for (int mi = 0; mi < 4; ++mi)
#pragma unroll
    for (int ni = 0; ni < 4; ++ni) {
      int i = i0 + wm * 64 + mi * 16 + lh * 4;
      int j = j0 + wn * 64 + ni * 16 + lr;
#pragma unroll
      for (int q = 0; q < 4; ++q)
        Sb[(size_t)(i + q) * NHW + j] = acc[mi][ni][q];
    }
}

// ---- row softmax (dual-buffer), f32 -> f16 attn written in-place ----
__global__ __launch_bounds__(256) void k_softmax(
    float* __restrict__ S0, float* __restrict__ S1) {
  const int rid = blockIdx.x;
  const int ROWS = NB * NHW;
  float* rp = (rid < ROWS ? S0 : S1) + (size_t)(rid < ROWS ? rid : rid - ROWS) * NHW;
  const int t = threadIdx.x;
  float v[9];
  float m = -3.4e38f;
#pragma unroll
  for (int k = 0; k < 9; ++k) { v[k] = rp[t + 256 * k]; m = fmaxf(m, v[k]); }
#pragma unroll
  for (int off = 32; off > 0; off >>= 1) m = fmaxf(m, __shfl_xor(m, off));
  __shared__ float red[4];
  __shared__ float red2[4];
  const int wv = t >> 6, ln = t & 63;
  if (ln == 0) red[wv] = m;
  __syncthreads();
  m = fmaxf(fmaxf(red[0], red[1]), fmaxf(red[2], red[3]));
  float s = 0.f;
#pragma unroll
  for (int k = 0; k < 9; ++k) { v[k] = expf(v[k] - m); s += v[k]; }
#pragma unroll
  for (int off = 32; off > 0; off >>= 1) s += __shfl_xor(s, off);
  if (ln == 0) red2[wv] = s;
  __syncthreads();
  float inv = 1.0f / (red2[0] + red2[1] + red2[2] + red2[3]);
  f16* op = (f16*)rp;
#pragma unroll
  for (int k = 0; k < 9; ++k) op[t + 256 * k] = (f16)(v[k] * inv);
}

// ---- PV r9: B in registers (direct global), A via glds ring-3 LDS ----
// BM=256 (c), BN=256 (i), BK=64 (j). 512 threads = 8 waves (2M x 4N), 128x64/wave.
// LDS: A ring-3, slot = t%3, 32KB each (96 KB total). 1 barrier/tile.
// Per tile: p0 {rdA mh0, issue B(t+1)->reg | MFMA 32 on B(t)},
//           p1 {rdA mh1, stage A(t+2) | MFMA 32 | vmcnt(12) | s_barrier}.
// vmcnt queue at tile end: [A(t+1) 4, B(t+1) 8, A(t+2) 4] -> vmcnt(12) retires A(t+1).
__global__ __launch_bounds__(512, 2) void k_pv8(
    const f16* __restrict__ V0, const f16* __restrict__ V1,
    const float* __restrict__ S0, const float* __restrict__ S1,
    float* __restrict__ out, int ndirs, long long ob0, long long ob1) {
  extern __shared__ __align__(16) f16 SH[];  // 3 * 16384 f16 = 96 KB

  const int nwg = ndirs * 288;
  const int bid = blockIdx.x;
  const int wg = (bid & 7) * (nwg >> 3) + (bid >> 3);  // XCD swizzle (nwg%8==0)
  const int n = wg % 9;
  const int r1 = wg / 9;
  const int m = r1 & 7;
  const int r2 = r1 >> 3;
  const int b = r2 & 3;
  const int dir = r2 >> 2;

  const f16* Vb = (dir ? V1 : V0) + (size_t)b * NC * NHW;
  const char* Sb = (const char*)(dir ? S1 : S0) + (size_t)b * NHW * NHW * 4;
  const long long obase = dir ? ob1 : ob0;
  const int c0 = m * 256, i0 = n * 256;
  const int tid = threadIdx.x, wv = tid >> 6, ln = tid & 63;
  const int lr = ln & 15, lg = ln >> 4;
  const int wm = wv >> 2, wn = wv & 3;

  // A staging map: chunk = 64 rows x 128 B; thread covers (fr, (tid&7)*16 bytes)
  const int fr = tid >> 3;
  const int scolb = ((tid & 7) * 16) ^ ((fr & 7) << 4);  // pre-swizzled source col
  const f16* aSrc = Vb + (size_t)(c0 + fr) * NHW + (scolb >> 1);
  const int ldsW = wv * 512;

  auto stA = [&](int slot, int t2, int r) {
    glds16(aSrc + (size_t)r * 64 * NHW + (size_t)t2 * 64,
           SH + slot * 16384 + r * 4096 + ldsW);
  };
  auto rdA = [&](int slot, int mi, int ks) -> f16x8 {
    int row = wm * 128 + mi * 16 + lr;
    int colb = (ks * 64 + lg * 16) ^ ((row & 7) << 4);
    return *(const f16x8*)((const char*)(SH + slot * 16384) + row * 128 + colb);
  };
  // B direct-load base: lane reads attn[i0 + wn*64 + ni*16 + lr][k = t*32*2 ...]
  const char* bR = Sb + (size_t)(i0 + wn * 64 + lr) * 9216 + lg * 16;
  auto ldB = [&](int t2, int ni, int ks) -> f16x8 {
    return *(const f16x8*)(bR + (size_t)ni * (16 * 9216) + t2 * 128 + ks * 64);
  };

  f32x4 acc[8][4];
#pragma unroll
  for (int mi = 0; mi < 8; ++mi)
#pragma unroll
    for (int ni = 0; ni < 4; ++ni)
#pragma unroll
      for (int q = 0; q < 4; ++q) acc[mi][ni][q] = 0.f;

  f16x8 BA[4][2], BB[4][2];

  // prologue: stage A(0), A(1); load B(0) into BA; wait A(0); barrier.
#pragma unroll
  for (int r = 0; r < 4; ++r) stA(0, 0, r);
#pragma unroll
  for (int r = 0; r < 4; ++r) stA(1, 1, r);
#pragma unroll
  for (int ni = 0; ni < 4; ++ni) {
    BA[ni][0] = ldB(0, ni, 0);
    BA[ni][1] = ldB(0, ni, 1);
  }
  asm volatile("s_waitcnt vmcnt(12)" ::: "memory");  // A(0) landed
  asm volatile("s_barrier" ::: "memory");
  __builtin_amdgcn_sched_barrier(0);

  auto tile = [&](int t, f16x8 (&Bc)[4][2], f16x8 (&Bn)[4][2]) {
    const int slot = t % 3;
    f16x8 Af[4][2];
    // ---- p0: rdA mh0; issue B(t+1); MFMA 32 on Bc ----
#pragma unroll
    for (int mi = 0; mi < 4; ++mi) { Af[mi][0] = rdA(slot, mi, 0); Af[mi][1] = rdA(slot, mi, 1); }
    if (t + 1 < NT) {
#pragma unroll
      for (int ni = 0; ni < 4; ++ni) {
        Bn[ni][0] = ldB(t + 1, ni, 0);
        Bn[ni][1] = ldB(t + 1, ni, 1);
      }
    }
    __builtin_amdgcn_s_setprio(1);
#pragma unroll
    for (int ks = 0; ks < 2; ++ks)
#pragma unroll
      for (int mi = 0; mi < 4; ++mi)
#pragma unroll
        for (int ni = 0; ni < 4; ++ni)
          acc[mi][ni] = __builtin_amdgcn_mfma_f32_16x16x32_f16(Af[mi][ks], Bc[ni][ks], acc[mi][ni], 0, 0, 0);
    __builtin_amdgcn_s_setprio(0);
    // ---- p1: rdA mh1; stage A(t+2); MFMA 32; one counted wait; barrier ----
#pragma unroll
    for (int mi = 0; mi < 4; ++mi) { Af[mi][0] = rdA(slot, 4 + mi, 0); Af[mi][1] = rdA(slot, 4 + mi, 1); }
    if (t + 2 < NT) {
      int s2 = (t + 2) % 3;
#pragma unroll
      for (int r = 0; r < 4; ++r) stA(s2, t + 2, r);
    }
    __builtin_amdgcn_s_setprio(1);
#pragma unroll
    for (int ks = 0; ks < 2; ++ks)
#pragma unroll
      for (int mi = 0; mi < 4; ++mi)
#pragma unroll
        for (int ni = 0; ni < 4; ++ni)
          acc[4 + mi][ni] = __builtin_amdgcn_mfma_f32_16x16x32_f16(Af[mi][ks], Bc[ni][ks], acc[4 + mi][ni], 0, 0, 0);
    __builtin_amdgcn_s_setprio(0);
    if (t + 2 < NT)      { asm volatile("s_waitcnt vmcnt(12)" ::: "memory"); }
    else if (t + 1 < NT) { asm volatile("s_waitcnt vmcnt(8)" ::: "memory"); }
    asm volatile("s_barrier" ::: "memory");
    __builtin_amdgcn_sched_barrier(0);
  };

  for (int t = 0; t < NT; t += 2) {
    tile(t, BA, BB);
    tile(t + 1, BB, BA);
  }

  float* ob = out + obase + (size_t)b * (2 * NC * NHW);
#pragma unroll
  for (int mi = 0; mi < 8; ++mi)
#pragma unroll
    for (int ni = 0; ni < 4; ++ni) {
      int c = c0 + wm * 128 + mi * 16 + lg * 4;
      int i = i0 + wn * 64 + ni * 16 + lr;
#pragma unroll
      for (int q = 0; q < 4; ++q)
        ob[(size_t)(NC + c + q) * NHW + i] = acc[mi][ni][q];
    }
}

extern "C" void kernel_launch(void* const* d_in, const int* in_sizes, int n_in,
                              void* d_out, int out_size, void* d_ws, size_t ws_size,
                              hipStream_t stream) {
  const float* xl = (const float*)d_in[0];
  const float* xr = (const float*)d_in[1];
  const float* wq = (const float*)d_in[2];
  const float* bq = (const float*)d_in[3];
  const float* wk = (const float*)d_in[4];
  const float* bk = (const float*)d_in[5];
  float* out = (float*)d_out;
  char* ws = (char*)d_ws;

  const size_t XH_BYTES = (size_t)2 * NB * NC * NHW * 2;   // 75,497,472
  const size_t WS_BYTES = (size_t)512 * NC * 2;            //  2,097,152
  const size_t YT_BYTES = (size_t)2 * NB * NHW * 512 * 2;  // 18,874,368
  const size_t S_BYTES  = (size_t)NB * NHW * NHW * 4;      // 84,934,656

  f16* Xh = (f16*)ws;
  f16* Ws_ = (f16*)(ws + XH_BYTES);
  f16* Yt = (f16*)(ws + XH_BYTES + WS_BYTES);
  char* rest = ws + XH_BYTES + WS_BYTES + YT_BYTES;

  const size_t xh_side = (size_t)NB * NC * NHW;
  const long long obA = (long long)NB * 2 * NC * NHW;  // right_attended weighted half
  const long long obB = 0;                             // left_attended weighted half

  const bool merged = ws_size >= XH_BYTES + WS_BYTES + YT_BYTES + 2 * S_BYTES;

  if (merged) {
    float* S0 = (float*)rest;
    char* rest2 = rest + S_BYTES;
    f16* Xt = (f16*)rest2;   // aliases S1 (consumed by proj before scores dir-1)
    float* S1 = (float*)rest2;

    k_prep<<<dim3(36, 32, 8), dim3(256), 0, stream>>>(xl, xr, out, Xh, Xt);
    k_w16<<<dim3(1024), dim3(256), 0, stream>>>(wq, wk, Ws_);
    k_proj<<<dim3(72, 4, 2), dim3(256), 0, stream>>>(Ws_, Xt, bq, bk, Yt);

    k_scores<<<dim3(18, 18, 8), dim3(256), 0, stream>>>(Yt, S0, S1, 0);
    k_softmax<<<dim3(2 * NB * NHW), dim3(256), 0, stream>>>(S0, S1);
    k_pv8<<<dim3(576), dim3(512), 98304, stream>>>(
        Xh + xh_side, Xh, S0, S1, out, 2, obA, obB);
  } else {
    f16* Xt = (f16*)rest;   // aliases S
    float* S = (float*)rest;

    k_prep<<<dim3(36, 32, 8), dim3(256), 0, stream>>>(xl, xr, out, Xh, Xt);
    k_w16<<<dim3(1024), dim3(256), 0, stream>>>(wq, wk, Ws_);
    k_proj<<<dim3(72, 4, 2), dim3(256), 0, stream>>>(Ws_, Xt, bq, bk, Yt);

    k_scores<<<dim3(18, 18, 4), dim3(256), 0, stream>>>(Yt, S, S, 0);
    k_softmax<<<dim3(NB * NHW), dim3(256), 0, stream>>>(S, S);
    k_pv8<<<dim3(288), dim3(512), 98304, stream>>>(
        Xh + xh_side, Xh + xh_side, S, S, out, 1, obA, obA);

    k_scores<<<dim3(18, 18, 4), dim3(256), 0, stream>>>(Yt, S, S, 1);
    k_softmax<<<dim3(NB * NHW), dim3(256), 0, stream>>>(S, S);
    k_pv8<<<dim3(288), dim3(512), 98304, stream>>>(
        Xh, Xh, S, S, out, 1, obB, obB);
  }
}

// Round 10
// 423.196 us; speedup vs baseline: 1.3271x; 1.3271x over previous
//
#include <hip/hip_runtime.h>
#include <stdint.h>

// CoAttention, MI355X. B=4, C=2048, H=W=48 (HW=2304), HC=256.
// r10: revert PV to r8 LDS-staged schedule (r9's B-direct-global regressed:
// scattered 64B segments + compiler/hand vmcnt mixing). Change BN 256->192:
// 768 blocks = exactly 3 rounds on 256 CUs (packing 75%->100%).
// 7 chunks/tile (A0-3,B0-2), same 2-tile-ahead ledger with vmcnt(7).

#define NB 4
#define NC 2048
#define NHW 2304
#define NHC 256
#define NT 36  // K tiles of 64 over NHW

typedef _Float16 f16;
typedef __attribute__((ext_vector_type(4))) _Float16 f16x4;
typedef __attribute__((ext_vector_type(8))) _Float16 f16x8;
typedef __attribute__((ext_vector_type(4))) float f32x4;

static __device__ __forceinline__ void glds16(const void* g, void* lds) {
  __builtin_amdgcn_global_load_lds(
      (const __attribute__((address_space(1))) uint32_t*)g,
      (__attribute__((address_space(3))) uint32_t*)lds, 16, 0, 0);
}

// ---- prep: copy originals to out, X->f16 (Xh, [c][hw]) and X^T->f16 (Xt, [hw][c]) ----
__global__ __launch_bounds__(256) void k_prep(
    const float* __restrict__ xl, const float* __restrict__ xr,
    float* __restrict__ out, f16* __restrict__ Xh, f16* __restrict__ Xt) {
  const int z = blockIdx.z, side = z >> 2, b = z & 3;
  const float* X = (side ? xr : xl) + (size_t)b * NC * NHW;
  const int hw0 = blockIdx.x * 64, c0 = blockIdx.y * 64;
  const int t = threadIdx.x;
  const int colb = (t & 15) * 4;
  const int r0 = t >> 4;
  __shared__ f16 Lt[64 * 64];
  float* outb = out + (size_t)side * ((size_t)NB * 2 * NC * NHW) + (size_t)b * (2 * NC * NHW);
  f16* Xhb = Xh + (size_t)side * ((size_t)NB * NC * NHW) + (size_t)b * NC * NHW;
  f16* Xtb = Xt + (size_t)side * ((size_t)NB * NHW * NC) + (size_t)b * NHW * NC;
#pragma unroll
  for (int p = 0; p < 4; ++p) {
    int r = r0 + p * 16;
    size_t go = (size_t)(c0 + r) * NHW + hw0 + colb;
    float4 v = *(const float4*)&X[go];
    *(float4*)&outb[go] = v;
    f16x4 h; h[0] = (f16)v.x; h[1] = (f16)v.y; h[2] = (f16)v.z; h[3] = (f16)v.w;
    *(f16x4*)&Xhb[go] = h;
#pragma unroll
    for (int j = 0; j < 4; ++j) {
      int row = colb + j;
      int byte = row * 128 + ((r * 2) ^ ((((row >> 2) & 7)) << 4));
      *(f16*)((char*)Lt + byte) = h[j];
    }
  }
  __syncthreads();
#pragma unroll
  for (int p = 0; p < 2; ++p) {
    int idx = p * 256 + t;
    int row = idx >> 3, ch = idx & 7;
    int byte = row * 128 + (((ch ^ ((row >> 2) & 7))) << 4);
    f16x8 vv = *(const f16x8*)((char*)Lt + byte);
    *(f16x8*)&Xtb[(size_t)(hw0 + row) * NC + c0 + ch * 8] = vv;
  }
}

// ---- W stack to f16: Ws[512][2048] ----
__global__ __launch_bounds__(256) void k_w16(
    const float* __restrict__ wq, const float* __restrict__ wk, f16* __restrict__ Ws) {
  const int N4 = NHC * NC / 4;
  int idx = blockIdx.x * 256 + threadIdx.x;
  const float* src = (idx < N4) ? wq : wk;
  int e4 = (idx < N4) ? idx : idx - N4;
  float4 v = ((const float4*)src)[e4];
  f16x4 h; h[0] = (f16)v.x; h[1] = (f16)v.y; h[2] = (f16)v.z; h[3] = (f16)v.w;
  ((f16x4*)Ws)[idx] = h;
}

// ---- proj (both sides, z=side): Yt[i][512] = Ws x Xt + bias (128x128, BK=32) ----
__global__ __launch_bounds__(256) void k_proj(
    const f16* __restrict__ Ws, const f16* __restrict__ Xt0,
    const float* __restrict__ bq, const float* __restrict__ bk,
    f16* __restrict__ Yt0) {
  __shared__ f16 LA[2][128 * 32], LB[2][128 * 32];
  const int side = blockIdx.z;
  const f16* Xt = Xt0 + (size_t)side * ((size_t)NB * NHW * NC);
  f16* Yt = Yt0 + (size_t)side * ((size_t)NB * NHW * 512);
  const int n0 = blockIdx.x * 128;
  const int m0 = blockIdx.y * 128;
  const int tid = threadIdx.x, wv = tid >> 6, ln = tid & 63;
  const int lr = ln & 15, lh = ln >> 4;
  const int wm = wv >> 1, wn = wv & 1;
  f32x4 acc[4][4];
#pragma unroll
  for (int mi = 0; mi < 4; ++mi)
#pragma unroll
    for (int ni = 0; ni < 4; ++ni)
#pragma unroll
      for (int q = 0; q < 4; ++q) acc[mi][ni][q] = 0.f;

  auto stage = [&](int bi, int ks) {
    int k0 = ks * 32;
#pragma unroll
    for (int rep = 0; rep < 2; ++rep) {
      int u = rep * 256 + wv * 64 + ln;
      int r = u >> 2, k8 = (u & 3) * 8;
      int ub8 = (rep * 256 + wv * 64) * 8;
      glds16(Ws + (size_t)(m0 + r) * NC + k0 + k8, &LA[bi][ub8]);
      glds16(Xt + (size_t)(n0 + r) * NC + k0 + k8, &LB[bi][ub8]);
    }
  };
  auto compute = [&](int bi) {
    f16x8 af[4], bf[4];
#pragma unroll
    for (int mi = 0; mi < 4; ++mi)
      af[mi] = *(const f16x8*)&LA[bi][(wm * 64 + mi * 16 + lr) * 32 + lh * 8];
#pragma unroll
    for (int ni = 0; ni < 4; ++ni)
      bf[ni] = *(const f16x8*)&LB[bi][(wn * 64 + ni * 16 + lr) * 32 + lh * 8];
#pragma unroll
    for (int mi = 0; mi < 4; ++mi)
#pragma unroll
      for (int ni = 0; ni < 4; ++ni)
        acc[mi][ni] = __builtin_amdgcn_mfma_f32_16x16x32_f16(af[mi], bf[ni], acc[mi][ni], 0, 0, 0);
  };

  stage(0, 0);
  __syncthreads();
  int cur = 0;
  for (int ks = 0; ks < 63; ++ks) {
    stage(cur ^ 1, ks + 1);
    compute(cur);
    __syncthreads();
    cur ^= 1;
  }
  compute(cur);

#pragma unroll
  for (int mi = 0; mi < 4; ++mi)
#pragma unroll
    for (int ni = 0; ni < 4; ++ni) {
      int ob = m0 + wm * 64 + mi * 16 + lh * 4;
      int i = n0 + wn * 64 + ni * 16 + lr;
      f16x4 hv;
#pragma unroll
      for (int q = 0; q < 4; ++q) {
        int o = ob + q;
        float bias = (o < NHC) ? bq[o] : bk[o - NHC];
        hv[q] = (f16)(acc[mi][ni][q] + bias);
      }
      *(f16x4*)&Yt[(size_t)i * 512 + ob] = hv;
    }
}

// ---- scores (both dirs, z=dir*4+b offset by dir0): S[b][i][j] = sum_hc Q.K ----
__global__ __launch_bounds__(256) void k_scores(
    const f16* __restrict__ Yt, float* __restrict__ S0, float* __restrict__ S1,
    int dir0) {
  __shared__ f16 LA[2][128 * 32], LB[2][128 * 32];
  const size_t YTS = (size_t)NB * NHW * 512;
  const int z = blockIdx.z;
  const int dir = dir0 + (z >> 2);
  const int b = z & 3;
  const int i0 = blockIdx.x * 128, j0 = blockIdx.y * 128;
  const int tid = threadIdx.x, wv = tid >> 6, ln = tid & 63;
  const int lr = ln & 15, lh = ln >> 4;
  const int wm = wv >> 1, wn = wv & 1;
  const f16* Qb = Yt + (size_t)dir * YTS + (size_t)b * NHW * 512;
  const f16* Kb = Yt + (size_t)(1 - dir) * YTS + NHC + (size_t)b * NHW * 512;
  f32x4 acc[4][4];
#pragma unroll
  for (int mi = 0; mi < 4; ++mi)
#pragma unroll
    for (int ni = 0; ni < 4; ++ni)
#pragma unroll
      for (int q = 0; q < 4; ++q) acc[mi][ni][q] = 0.f;

  auto stage = [&](int bi, int ks) {
    int k0 = ks * 32;
#pragma unroll
    for (int rep = 0; rep < 2; ++rep) {
      int u = rep * 256 + wv * 64 + ln;
      int r = u >> 2, k8 = (u & 3) * 8;
      int ub8 = (rep * 256 + wv * 64) * 8;
      glds16(Qb + (size_t)(i0 + r) * 512 + k0 + k8, &LA[bi][ub8]);
      glds16(Kb + (size_t)(j0 + r) * 512 + k0 + k8, &LB[bi][ub8]);
    }
  };
  auto compute = [&](int bi) {
    f16x8 af[4], bf[4];
#pragma unroll
    for (int mi = 0; mi < 4; ++mi)
      af[mi] = *(const f16x8*)&LA[bi][(wm * 64 + mi * 16 + lr) * 32 + lh * 8];
#pragma unroll
    for (int ni = 0; ni < 4; ++ni)
      bf[ni] = *(const f16x8*)&LB[bi][(wn * 64 + ni * 16 + lr) * 32 + lh * 8];
#pragma unroll
    for (int mi = 0; mi < 4; ++mi)
#pragma unroll
      for (int ni = 0; ni < 4; ++ni)
        acc[mi][ni] = __builtin_amdgcn_mfma_f32_16x16x32_f16(af[mi], bf[ni], acc[mi][ni], 0, 0, 0);
  };

  stage(0, 0);
  __syncthreads();
  int cur = 0;
  for (int ks = 0; ks < 7; ++ks) {
    stage(cur ^ 1, ks + 1);
    compute(cur);
    __syncthreads();
    cur ^= 1;
  }
  compute(cur);

  float* Sb = (dir ? S1 : S0) + (size_t)b * NHW * NHW;
#pragma unroll
  for (int mi = 0; mi < 4; ++mi)
#pragma unroll
    for (int ni = 0; ni < 4; ++ni) {
      int i = i0 + wm * 64 + mi * 16 + lh * 4;
      int j = j0 + wn * 64 + ni * 16 + lr;
#pragma unroll
      for (int q = 0; q < 4; ++q)
        Sb[(size_t)(i + q) * NHW + j] = acc[mi][ni][q];
    }
}

// ---- row softmax (dual-buffer), f32 -> f16 attn written in-place ----
__global__ __launch_bounds__(256) void k_softmax(
    float* __restrict__ S0, float* __restrict__ S1) {
  const int rid = blockIdx.x;
  const int ROWS = NB * NHW;
  float* rp = (rid < ROWS ? S0 : S1) + (size_t)(rid < ROWS ? rid : rid - ROWS) * NHW;
  const int t = threadIdx.x;
  float v[9];
  float m = -3.4e38f;
#pragma unroll
  for (int k = 0; k < 9; ++k) { v[k] = rp[t + 256 * k]; m = fmaxf(m, v[k]); }
#pragma unroll
  for (int off = 32; off > 0; off >>= 1) m = fmaxf(m, __shfl_xor(m, off));
  __shared__ float red[4];
  __shared__ float red2[4];
  const int wv = t >> 6, ln = t & 63;
  if (ln == 0) red[wv] = m;
  __syncthreads();
  m = fmaxf(fmaxf(red[0], red[1]), fmaxf(red[2], red[3]));
  float s = 0.f;
#pragma unroll
  for (int k = 0; k < 9; ++k) { v[k] = expf(v[k] - m); s += v[k]; }
#pragma unroll
  for (int off = 32; off > 0; off >>= 1) s += __shfl_xor(s, off);
  if (ln == 0) red2[wv] = s;
  __syncthreads();
  float inv = 1.0f / (red2[0] + red2[1] + red2[2] + red2[3]);
  f16* op = (f16*)rp;
#pragma unroll
  for (int k = 0; k < 9; ++k) op[t + 256 * k] = (f16)(v[k] * inv);
}

// ---- PV, 256x192, 4 phases, r8 schedule, 2-tile-ahead chunk ledger ----
// BM=256 (c), BN=192 (i), BK=64 (j). 512 threads = 8 waves (2M x 4N), 128x48/wave.
// LDS: A[2] 32KB @ 0/32KB(byte), B[2] 24KB @ 64KB. Total 112 KB.
// Chunks/tile: A0-3 + B0-2 = 7. Reads: p0 {A mh0 + B ni0,1}, p1 {B ni2},
// p2 {A mh1}, p3 {none}. Stages(t+2): p1 {A0,A2}, p2 {B0,B1}, p3 {A1,A3,B2}.
// ONE wait/tile: vmcnt(7) at p3-end retires generation t+1.
__global__ __launch_bounds__(512, 2) void k_pv8(
    const f16* __restrict__ V0, const f16* __restrict__ V1,
    const float* __restrict__ S0, const float* __restrict__ S1,
    float* __restrict__ out, int ndirs, long long ob0, long long ob1) {
  extern __shared__ __align__(16) f16 SH[];

  const int nwg = ndirs * 384;
  const int bid = blockIdx.x;
  const int wg = (bid & 7) * (nwg >> 3) + (bid >> 3);  // XCD swizzle (nwg%8==0)
  const int n = wg % 12;
  const int r1 = wg / 12;
  const int m = r1 & 7;
  const int r2 = r1 >> 3;
  const int b = r2 & 3;
  const int dir = r2 >> 2;

  const f16* Vb = (dir ? V1 : V0) + (size_t)b * NC * NHW;
  const char* Sb = (const char*)(dir ? S1 : S0) + (size_t)b * NHW * NHW * 4;
  const long long obase = dir ? ob1 : ob0;
  const int c0 = m * 256, i0 = n * 192;
  const int tid = threadIdx.x, wv = tid >> 6, ln = tid & 63;
  const int lr = ln & 15, lg = ln >> 4;
  const int wm = wv >> 2, wn = wv & 3;

  const int fr = tid >> 3;
  const int scolb = ((tid & 7) * 16) ^ ((fr & 7) << 4);  // pre-swizzled source col
  const f16* aSrc = Vb + (size_t)(c0 + fr) * NHW + (scolb >> 1);
  const char* bSrc = Sb + (size_t)(i0 + fr) * 9216 + scolb;
  const int ldsW = wv * 512;

  auto stA = [&](int bf, int t2, int r) {
    glds16(aSrc + (size_t)r * 64 * NHW + (size_t)t2 * 64,
           SH + bf * 16384 + r * 4096 + ldsW);
  };
  auto stB = [&](int bf, int t2, int r) {
    glds16(bSrc + (size_t)r * 64 * 9216 + t2 * 128,
           SH + 32768 + bf * 12288 + r * 4096 + ldsW);
  };
  auto rdA = [&](int bf, int mi, int ks) -> f16x8 {
    int row = wm * 128 + mi * 16 + lr;
    int colb = (ks * 64 + lg * 16) ^ ((row & 7) << 4);
    return *(const f16x8*)((const char*)(SH + bf * 16384) + row * 128 + colb);
  };
  auto rdB = [&](int bf, int ni, int ks) -> f16x8 {
    int row = wn * 48 + ni * 16 + lr;
    int colb = (ks * 64 + lg * 16) ^ ((row & 7) << 4);
    return *(const f16x8*)((const char*)(SH + 32768 + bf * 12288) + row * 128 + colb);
  };

  f32x4 acc[8][3];
#pragma unroll
  for (int mi = 0; mi < 8; ++mi)
#pragma unroll
    for (int ni = 0; ni < 3; ++ni)
#pragma unroll
      for (int q = 0; q < 4; ++q) acc[mi][ni][q] = 0.f;

  f16x8 Af[4][2], Bn0[2][2], Bn1[1][2];

  // prologue: gen-tile0 (7 chunks), gen-tile1 (7 chunks), retire tile0, barrier
#pragma unroll
  for (int r = 0; r < 4; ++r) stA(0, 0, r);
#pragma unroll
  for (int r = 0; r < 3; ++r) stB(0, 0, r);
#pragma unroll
  for (int r = 0; r < 4; ++r) stA(1, 1, r);
#pragma unroll
  for (int r = 0; r < 3; ++r) stB(1, 1, r);
  asm volatile("s_waitcnt vmcnt(7)" ::: "memory");  // tile 0 landed
  asm volatile("s_barrier" ::: "memory");

  for (int t = 0; t < NT; ++t) {
    const int cb = t & 1;
    const bool s2 = (t + 2 < NT);
    // ---------- p0: (mh0, nh0={0,1}) ----------
#pragma unroll
    for (int mi = 0; mi < 4; ++mi) { Af[mi][0] = rdA(cb, mi, 0); Af[mi][1] = rdA(cb, mi, 1); }
#pragma unroll
    for (int ni = 0; ni < 2; ++ni) { Bn0[ni][0] = rdB(cb, ni, 0); Bn0[ni][1] = rdB(cb, ni, 1); }
    asm volatile("s_barrier" ::: "memory");
    asm volatile("s_waitcnt lgkmcnt(0)" ::: "memory");
    __builtin_amdgcn_sched_barrier(0);
    __builtin_amdgcn_s_setprio(1);
#pragma unroll
    for (int ks = 0; ks < 2; ++ks)
#pragma unroll
      for (int mi = 0; mi < 4; ++mi)
#pragma unroll
        for (int ni = 0; ni < 2; ++ni)
          acc[mi][ni] = __builtin_amdgcn_mfma_f32_16x16x32_f16(Af[mi][ks], Bn0[ni][ks], acc[mi][ni], 0, 0, 0);
    __builtin_amdgcn_s_setprio(0);
    asm volatile("s_barrier" ::: "memory");
    // ---------- p1: (mh0, nh1={2}) ----------
    Bn1[0][0] = rdB(cb, 2, 0); Bn1[0][1] = rdB(cb, 2, 1);
    if (s2) { stA(cb, t + 2, 0); stA(cb, t + 2, 2); }
    asm volatile("s_barrier" ::: "memory");
    asm volatile("s_waitcnt lgkmcnt(0)" ::: "memory");
    __builtin_amdgcn_sched_barrier(0);
    __builtin_amdgcn_s_setprio(1);
#pragma unroll
    for (int ks = 0; ks < 2; ++ks)
#pragma unroll
      for (int mi = 0; mi < 4; ++mi)
        acc[mi][2] = __builtin_amdgcn_mfma_f32_16x16x32_f16(Af[mi][ks], Bn1[0][ks], acc[mi][2], 0, 0, 0);
    __builtin_amdgcn_s_setprio(0);
    asm volatile("s_barrier" ::: "memory");
    // ---------- p2: (mh1, nh1={2}) ----------
#pragma unroll
    for (int mi = 0; mi < 4; ++mi) { Af[mi][0] = rdA(cb, 4 + mi, 0); Af[mi][1] = rdA(cb, 4 + mi, 1); }
    if (s2) { stB(cb, t + 2, 0); stB(cb, t + 2, 1); }
    asm volatile("s_barrier" ::: "memory");
    asm volatile("s_waitcnt lgkmcnt(0)" ::: "memory");
    __builtin_amdgcn_sched_barrier(0);
    __builtin_amdgcn_s_setprio(1);
#pragma unroll
    for (int ks = 0; ks < 2; ++ks)
#pragma unroll
      for (int mi = 0; mi < 4; ++mi)
        acc[4 + mi][2] = __builtin_amdgcn_mfma_f32_16x16x32_f16(Af[mi][ks], Bn1[0][ks], acc[4 + mi][2], 0, 0, 0);
    __builtin_amdgcn_s_setprio(0);
    asm volatile("s_barrier" ::: "memory");
    // ---------- p3: (mh1, nh0) — no reads; stage A1,A3,B2(t+2); ONE wait ----------
    if (s2) { stA(cb, t + 2, 1); stA(cb, t + 2, 3); stB(cb, t + 2, 2); }
    __builtin_amdgcn_s_setprio(1);
#pragma unroll
    for (int ks = 0; ks < 2; ++ks)
#pragma unroll
      for (int mi = 0; mi < 4; ++mi)
#pragma unroll
        for (int ni = 0; ni < 2; ++ni)
          acc[4 + mi][ni] = __builtin_amdgcn_mfma_f32_16x16x32_f16(Af[mi][ks], Bn0[ni][ks], acc[4 + mi][ni], 0, 0, 0);
    __builtin_amdgcn_s_setprio(0);
    if (s2)                { asm volatile("s_waitcnt vmcnt(7)" ::: "memory"); }
    else if (t + 1 < NT)   { asm volatile("s_waitcnt vmcnt(0)" ::: "memory"); }
    asm volatile("s_barrier" ::: "memory");
  }

  float* ob = out + obase + (size_t)b * (2 * NC * NHW);
#pragma unroll
  for (int mi = 0; mi < 8; ++mi)
#pragma unroll
    for (int ni = 0; ni < 3; ++ni) {
      int c = c0 + wm * 128 + mi * 16 + lg * 4;
      int i = i0 + wn * 48 + ni * 16 + lr;
#pragma unroll
      for (int q = 0; q < 4; ++q)
        ob[(size_t)(NC + c + q) * NHW + i] = acc[mi][ni][q];
    }
}

extern "C" void kernel_launch(void* const* d_in, const int* in_sizes, int n_in,
                              void* d_out, int out_size, void* d_ws, size_t ws_size,
                              hipStream_t stream) {
  const float* xl = (const float*)d_in[0];
  const float* xr = (const float*)d_in[1];
  const float* wq = (const float*)d_in[2];
  const float* bq = (const float*)d_in[3];
  const float* wk = (const float*)d_in[4];
  const float* bk = (const float*)d_in[5];
  float* out = (float*)d_out;
  char* ws = (char*)d_ws;

  const size_t XH_BYTES = (size_t)2 * NB * NC * NHW * 2;   // 75,497,472
  const size_t WS_BYTES = (size_t)512 * NC * 2;            //  2,097,152
  const size_t YT_BYTES = (size_t)2 * NB * NHW * 512 * 2;  // 18,874,368
  const size_t S_BYTES  = (size_t)NB * NHW * NHW * 4;      // 84,934,656

  f16* Xh = (f16*)ws;
  f16* Ws_ = (f16*)(ws + XH_BYTES);
  f16* Yt = (f16*)(ws + XH_BYTES + WS_BYTES);
  char* rest = ws + XH_BYTES + WS_BYTES + YT_BYTES;

  const size_t xh_side = (size_t)NB * NC * NHW;
  const long long obA = (long long)NB * 2 * NC * NHW;  // right_attended weighted half
  const long long obB = 0;                             // left_attended weighted half

  const bool merged = ws_size >= XH_BYTES + WS_BYTES + YT_BYTES + 2 * S_BYTES;

  if (merged) {
    float* S0 = (float*)rest;
    char* rest2 = rest + S_BYTES;
    f16* Xt = (f16*)rest2;   // aliases S1 (consumed by proj before scores dir-1)
    float* S1 = (float*)rest2;

    k_prep<<<dim3(36, 32, 8), dim3(256), 0, stream>>>(xl, xr, out, Xh, Xt);
    k_w16<<<dim3(1024), dim3(256), 0, stream>>>(wq, wk, Ws_);
    k_proj<<<dim3(72, 4, 2), dim3(256), 0, stream>>>(Ws_, Xt, bq, bk, Yt);

    k_scores<<<dim3(18, 18, 8), dim3(256), 0, stream>>>(Yt, S0, S1, 0);
    k_softmax<<<dim3(2 * NB * NHW), dim3(256), 0, stream>>>(S0, S1);
    k_pv8<<<dim3(768), dim3(512), 114688, stream>>>(
        Xh + xh_side, Xh, S0, S1, out, 2, obA, obB);
  } else {
    f16* Xt = (f16*)rest;   // aliases S
    float* S = (float*)rest;

    k_prep<<<dim3(36, 32, 8), dim3(256), 0, stream>>>(xl, xr, out, Xh, Xt);
    k_w16<<<dim3(1024), dim3(256), 0, stream>>>(wq, wk, Ws_);
    k_proj<<<dim3(72, 4, 2), dim3(256), 0, stream>>>(Ws_, Xt, bq, bk, Yt);

    k_scores<<<dim3(18, 18, 4), dim3(256), 0, stream>>>(Yt, S, S, 0);
    k_softmax<<<dim3(NB * NHW), dim3(256), 0, stream>>>(S, S);
    k_pv8<<<dim3(384), dim3(512), 114688, stream>>>(
        Xh + xh_side, Xh + xh_side, S, S, out, 1, obA, obA);

    k_scores<<<dim3(18, 18, 4), dim3(256), 0, stream>>>(Yt, S, S, 1);
    k_softmax<<<dim3(NB * NHW), dim3(256), 0, stream>>>(S, S);
    k_pv8<<<dim3(384), dim3(512), 114688, stream>>>(
        Xh, Xh, S, S, out, 1, obB, obB);
  }
}